// Round 4
// baseline (1481.783 us; speedup 1.0000x reference)
//
#include <hip/hip_runtime.h>
#include <math.h>

#define LAYERS 2
#define NNEI 120
#define NPAD 128
#define ED 64
#define HD 128
#define NB 4096
#define F3 (3*HD)
#define SCALING 0.088388347648318447f
#define LN_EPS 1e-5f
#define T 1024
#define XP 68

typedef unsigned short u16;
typedef unsigned int u32;
typedef unsigned char u8;
typedef float f32x4 __attribute__((ext_vector_type(4)));
typedef short bf16x8 __attribute__((ext_vector_type(8)));

__device__ __forceinline__ float bf2f(u16 u) { return __uint_as_float(((u32)u) << 16); }
__device__ __forceinline__ u16 f2bf(float f) {
  __bf16 b = (__bf16)f;                       // HW RNE convert
  return __builtin_bit_cast(u16, b);
}
__device__ __forceinline__ u32 pk2bf(float lo, float hi) {
  return (u32)f2bf(lo) | ((u32)f2bf(hi) << 16);
}
__device__ __forceinline__ float gldr(const void* p, long i, bool f32) {
  return f32 ? ((const float*)p)[i] : bf2f(((const u16*)p)[i]);
}
__device__ __forceinline__ float red16sum(float v) {
  v += __shfl_xor(v, 1); v += __shfl_xor(v, 2);
  v += __shfl_xor(v, 4); v += __shfl_xor(v, 8);
  return v;
}

#define MFMA(a, b, d) (d) = __builtin_amdgcn_mfma_f32_16x16x32_bf16((a), (b), (d), 0, 0, 0)
#define WVM(n) asm volatile("s_waitcnt vmcnt(" #n ")" ::: "memory")
#define LBAR() do { asm volatile("s_waitcnt lgkmcnt(0)" ::: "memory"); \
                    __builtin_amdgcn_s_barrier(); } while (0)

__device__ __forceinline__ void gload_lds16(const u16* src, u16* dst) {
  __builtin_amdgcn_global_load_lds(
      (const __attribute__((address_space(1))) u32*)(const void*)src,
      (__attribute__((address_space(3))) u32*)(void*)dst, 16, 0, 0);
}

// XOR-swizzled u16 element offset inside a [128][128] tile:
// 16B chunk index ^= (row & 7). Same mapping on write and read.
__device__ __forceinline__ int swz(int row, int col) {
  return (row << 7) + ((((col >> 3) ^ row) & 7) << 3) + (col & 7);
}

// Stage one [64 col][64 k] hi-bf16 tile (8 KB) into sbuf. Waves 0..7 issue
// one global_load_lds each (1 KB). Linear LDS dest (rule #21); the k-chunk
// stored in slot s of col is s^(col&7) (pre-swizzled global source).
__device__ __forceinline__ void stage8k(const u16* __restrict__ src_base, long base,
                                        int kstride, u16* sbuf, int wave, int lane) {
  if (wave < 8) {
    const int col = 8 * wave + (lane >> 3);
    const int s = lane & 7;
    const u16* src = src_base + base + (long)col * kstride + 8 * (s ^ (col & 7));
    gload_lds16(src, sbuf + wave * 512);
  }
}
__device__ __forceinline__ bf16x8 rdfrag(const u16* sbuf, int col, int kchunk) {
  return *(const bf16x8*)(sbuf + col * 64 + 8 * (kchunk ^ (col & 7)));
}

// ---- detector: flags[0]=1 if float inputs are f32; flags[1]=1 if mask is byte ----
__global__ void detect_kernel(const u16* __restrict__ G,
                              const u8* __restrict__ mask,
                              int* __restrict__ flags) {
  __shared__ int sf[2];
  const int t = threadIdx.x;
  if (t < 2) sf[t] = 0;
  __syncthreads();
  int isf = 0;
  for (int i = t; i < 256; i += 256) {
    int e = (G[2 * i] >> 7) & 0xff;
    if (e >= 150) isf = 1;
  }
  int mb = 0;
  for (int i = t; i < 4096; i += 256) {
    if (i && (i & 3) && mask[i]) mb = 1;
  }
  if (isf) atomicOr(&sf[0], 1);
  if (mb) atomicOr(&sf[1], 1);
  __syncthreads();
  if (t < 2) flags[t] = sf[t];
}

// ---- prep: transposed hi-bf16 weights: wt[l][f][e], ow[l][e][h] ----
__global__ void prep_kernel(const void* __restrict__ in_w, const void* __restrict__ out_w,
                            u16* __restrict__ wt_hi, u16* __restrict__ ow_hi,
                            const int* __restrict__ flags) {
  const bool f32 = flags[0] != 0;
  const int i = blockIdx.x * blockDim.x + threadIdx.x;
  if (i < LAYERS * F3 * ED) {
    const int l = i / (F3 * ED);
    const int rem = i % (F3 * ED);
    const int f = rem / ED;
    const int e = rem % ED;
    const long src = (long)(l * ED + e) * F3 + f;
    const float w = f32 ? ((const float*)in_w)[src] : bf2f(((const u16*)in_w)[src]);
    wt_hi[i] = f2bf(w);
  }
  if (i < LAYERS * ED * HD) {
    const int l = i / (ED * HD);
    const int rem = i % (ED * HD);
    const int e = rem / HD;
    const int hh = rem % HD;
    const long src = (long)(l * HD + hh) * ED + e;
    const float w = f32 ? ((const float*)out_w)[src] : bf2f(((const u16*)out_w)[src]);
    ow_hi[i] = f2bf(w);
  }
}

__global__ __launch_bounds__(T) void nwa_kernel(
    const void* __restrict__ G, const void* __restrict__ mask,
    const void* __restrict__ rr,
    const void* __restrict__ in_b, const void* __restrict__ out_b,
    const void* __restrict__ ln_g, const void* __restrict__ ln_b,
    const u16* __restrict__ wt_hi, const u16* __restrict__ ow_hi,
    void* __restrict__ out, const int* __restrict__ flags)
{
  const bool f32f = flags[0] != 0;
  const bool mbyte = flags[1] != 0;

  __shared__ __align__(16) float x_s[NPAD][XP];   // f32 x / residual (rows 120..127 zero)
  __shared__ __align__(16) u16 q_s[NPAD * 128];   // q~ -> o   (swizzled)
  __shared__ __align__(16) u16 k_s[NPAD * 128];   // k^ -> aw  (swizzled)
  __shared__ __align__(16) u16 vT_s[NPAD * 128];  // v^ transposed [h][m] (swizzled)
  __shared__ __align__(16) u16 stg[3 * 4096];     // 3 x 8KB rotating stage buffers
  __shared__ __align__(16) float r_s[NPAD][4];
  __shared__ __align__(16) float pA[2][8][16];    // cross-half scratch
  __shared__ __align__(16) float pB[2][8][16];
  __shared__ int m_s[NPAD];

  const int b = blockIdx.x;
  const int t = threadIdx.x;
  const int wave = t >> 6;
  const int band = wave & 7;     // 16-row band
  const int half = wave >> 3;    // column half
  const int lane = t & 63;
  const int g = lane >> 4;
  const int c = lane & 15;

  // ---- prologue: load x (f32), r, mask; zero pads; stage layer-0 chunk c2 ----
  {
    const long gbase = (long)b * (NNEI * ED);
    for (int i = t; i < NNEI * ED; i += T)
      x_s[i >> 6][i & 63] = gldr(G, gbase + i, f32f);
    for (int i = t; i < (NPAD - NNEI) * ED; i += T)
      x_s[NNEI + (i >> 6)][i & 63] = 0.f;
    const long rbase = (long)b * (NNEI * 3);
    const long mbase = (long)b * NNEI;
    for (int i = t; i < NPAD; i += T) {
      if (i < NNEI) {
        r_s[i][0] = gldr(rr, rbase + i * 3 + 0, f32f);
        r_s[i][1] = gldr(rr, rbase + i * 3 + 1, f32f);
        r_s[i][2] = gldr(rr, rbase + i * 3 + 2, f32f);
        r_s[i][3] = 0.f;
        m_s[i] = mbyte ? (int)((const u8*)mask)[mbase + i] : ((const int*)mask)[mbase + i];
      } else {
        r_s[i][0] = 0.f; r_s[i][1] = 0.f; r_s[i][2] = 0.f; r_s[i][3] = 0.f;
        m_s[i] = 0;
      }
    }
  }
  stage8k(wt_hi, (long)2 * 4096, 64, stg, wave, lane);   // layer0 K-chunk -> buf0
  __syncthreads();                                        // full drain, once

  int vm4 = 0;
  #pragma unroll
  for (int mtl = 0; mtl < 4; ++mtl) vm4 |= (m_s[16 * (4 * half + mtl) + c] ? 1 : 0) << mtl;
  float qmr[4];
  #pragma unroll
  for (int r = 0; r < 4; ++r) qmr[r] = m_s[16 * band + 4 * g + r] ? 1.f : 0.f;

  for (int l = 0; l < LAYERS; ++l) {
    const long wofs = (long)l * (F3 * ED);
    const long bbase = (long)l * F3;
    const long oofs = (long)l * (ED * HD);
    const int base = l ? 2 : 0;                 // staging buffer phase: (l*8)%3
    const bool use_lo = f32f || (l > 0);

    // ---- layer-top: hoist ALL scalar global loads (keeps vmcnt counting exact) ----
    float bQv[4], bKv[4], bVv[4];
    #pragma unroll
    for (int j = 0; j < 4; ++j) {
      const int nt = 4 * (j >> 1) + 2 * half + (j & 1);
      bQv[j] = gldr(in_b, bbase + 16 * nt + c, f32f);
      bKv[j] = gldr(in_b, bbase + 128 + 16 * nt + c, f32f);
      bVv[j] = gldr(in_b, bbase + 256 + 16 * nt + c, f32f);
    }
    float obv[2], ggv[2], bbv[2];
    #pragma unroll
    for (int ntl = 0; ntl < 2; ++ntl) {
      const int e0 = 16 * (2 * half + ntl) + c;
      obv[ntl] = gldr(out_b, (long)l * ED + e0, f32f);
      ggv[ntl] = gldr(ln_g, (long)l * ED + e0, f32f);
      bbv[ntl] = gldr(ln_b, (long)l * ED + e0, f32f);
    }

    // ---- phase 1: qkv = x @ in_w  (chunk order K,K,V,V,Q,Q; counted-vmcnt pipeline)
    bf16x8 a_hi[2], a_lo[2];
    #pragma unroll
    for (int kf = 0; kf < 2; ++kf) {
      const float* xp = &x_s[16 * band + c][32 * kf + 8 * g];
      const f32x4 xa = *(const f32x4*)xp;
      const f32x4 xb = *(const f32x4*)(xp + 4);
      float xf[8] = {xa[0], xa[1], xa[2], xa[3], xb[0], xb[1], xb[2], xb[3]};
      #pragma unroll
      for (int j2 = 0; j2 < 8; ++j2) {
        const u16 h = f2bf(xf[j2]);
        a_hi[kf][j2] = (short)h;
        a_lo[kf][j2] = (short)0;
      }
      if (use_lo) {
        #pragma unroll
        for (int j2 = 0; j2 < 8; ++j2) {
          const u16 h = f2bf(xf[j2]);
          a_lo[kf][j2] = (short)f2bf(xf[j2] - bf2f(h));
        }
      }
    }
    f32x4 accQ[4], accB[4];
    #pragma unroll
    for (int j = 0; j < 4; ++j) { accQ[j] = (f32x4){0,0,0,0}; accB[j] = (f32x4){0,0,0,0}; }

    #pragma unroll
    for (int ss = 0; ss < 6; ++ss) {
      const int n = (ss + 2) % 6;   // 2,3=K 4,5=V 0,1=Q
      if (ss < 5) {
        stage8k(wt_hi, wofs + (long)((ss + 3) % 6) * 4096, 64,
                stg + ((base + ss + 1) % 3) * 4096, wave, lane);
        WVM(1);                     // drain chunk ss, keep chunk ss+1 in flight
      } else {
        stage8k(ow_hi, oofs, 128, stg + ((base + 6) % 3) * 4096, wave, lane);
        stage8k(ow_hi, oofs + 64, 128, stg + ((base + 7) % 3) * 4096, wave, lane);
        WVM(2);                     // drain chunk c1, keep ow0/ow1 in flight
      }
      LBAR();

      if (ss == 2) {   // K finalize: l2norm + store k^ (swizzled); reset accB
        const f32x4 sa = *(const f32x4*)&pA[0][band][4 * g];
        const f32x4 sb4 = *(const f32x4*)&pA[1][band][4 * g];
        float invr[4];
        #pragma unroll
        for (int r = 0; r < 4; ++r) invr[r] = rsqrtf(fmaxf(sa[r] + sb4[r], 1e-24f));
        #pragma unroll
        for (int j = 0; j < 4; ++j) {
          const int nt = 4 * (j >> 1) + 2 * half + (j & 1);
          #pragma unroll
          for (int r = 0; r < 4; ++r)
            k_s[swz(16 * band + 4 * g + r, 16 * nt + c)] = f2bf(accB[j][r] * invr[r]);
          accB[j] = (f32x4){0,0,0,0};
        }
      }
      if (ss == 4) {   // V finalize: l2norm + store transposed v^ (swizzled)
        const f32x4 sa = *(const f32x4*)&pB[0][band][4 * g];
        const f32x4 sb4 = *(const f32x4*)&pB[1][band][4 * g];
        float invr[4];
        #pragma unroll
        for (int r = 0; r < 4; ++r) invr[r] = rsqrtf(fmaxf(sa[r] + sb4[r], 1e-24f));
        #pragma unroll
        for (int j = 0; j < 4; ++j) {
          const int nt = 4 * (j >> 1) + 2 * half + (j & 1);
          const u32 p01 = pk2bf(accB[j][0] * invr[0], accB[j][1] * invr[1]);
          const u32 p23 = pk2bf(accB[j][2] * invr[2], accB[j][3] * invr[3]);
          const int o0 = swz(16 * nt + c, 16 * band + 4 * g);
          *(u32*)&vT_s[o0] = p01;
          *(u32*)&vT_s[o0 + 2] = p23;
        }
      }

      // consume chunk n
      {
        const u16* sb = stg + ((base + ss) % 3) * 4096;
        #pragma unroll
        for (int ctl = 0; ctl < 2; ++ctl) {
          const int col = 16 * (2 * half + ctl) + c;
          const int j = 2 * (n & 1) + ctl;
          const bf16x8 bh0 = rdfrag(sb, col, g);
          const bf16x8 bh1 = rdfrag(sb, col, 4 + g);
          f32x4 d = (n < 2) ? accQ[j] : accB[j];
          MFMA(a_hi[0], bh0, d); MFMA(a_hi[1], bh1, d);
          if (use_lo) { MFMA(a_lo[0], bh0, d); MFMA(a_lo[1], bh1, d); }
          if (n < 2) accQ[j] = d; else accB[j] = d;
        }
      }

      if (ss == 1 || ss == 3) {   // K/V bias + cross-half partial sum-of-squares
        const float* bv = (ss == 1) ? bKv : bVv;
        #pragma unroll
        for (int j = 0; j < 4; ++j) {
          accB[j][0] += bv[j]; accB[j][1] += bv[j];
          accB[j][2] += bv[j]; accB[j][3] += bv[j];
        }
        float* dst = (ss == 1) ? &pA[half][band][0] : &pB[half][band][0];
        #pragma unroll
        for (int r = 0; r < 4; ++r) {
          const float ssum = accB[0][r] * accB[0][r] + accB[1][r] * accB[1][r] +
                             accB[2][r] * accB[2][r] + accB[3][r] * accB[3][r];
          const float red = red16sum(ssum);
          if (c == 0) dst[4 * g + r] = red;
        }
      }
      if (ss == 5) {   // Q tail: bias, partial SS, store UNNORMALIZED q~
        #pragma unroll
        for (int j = 0; j < 4; ++j) {
          accQ[j][0] += bQv[j]; accQ[j][1] += bQv[j];
          accQ[j][2] += bQv[j]; accQ[j][3] += bQv[j];
        }
        #pragma unroll
        for (int r = 0; r < 4; ++r) {
          const float ssum = accQ[0][r] * accQ[0][r] + accQ[1][r] * accQ[1][r] +
                             accQ[2][r] * accQ[2][r] + accQ[3][r] * accQ[3][r];
          const float red = red16sum(ssum);
          if (c == 0) pA[half][band][4 * g + r] = red;
        }
        #pragma unroll
        for (int j = 0; j < 4; ++j) {
          const int nt = 4 * (j >> 1) + 2 * half + (j & 1);
          #pragma unroll
          for (int r = 0; r < 4; ++r)
            q_s[swz(16 * band + 4 * g + r, 16 * nt + c)] = f2bf(accQ[j][r]);
        }
      }
    }
    LBAR();   // B2: q~, |q|^2 partials visible

    // ---- QK^T (4 key-tiles per wave) ----
    float invq[4];
    {
      const f32x4 qa = *(const f32x4*)&pA[0][band][4 * g];
      const f32x4 qb = *(const f32x4*)&pA[1][band][4 * g];
      #pragma unroll
      for (int r = 0; r < 4; ++r)
        invq[r] = SCALING * rsqrtf(fmaxf(qa[r] + qb[r], 1e-24f));
    }
    f32x4 s4[4];
    {
      bf16x8 aq[4];
      #pragma unroll
      for (int kf = 0; kf < 4; ++kf)
        aq[kf] = *(const bf16x8*)&q_s[swz(16 * band + c, 8 * g + 32 * kf)];
      #pragma unroll
      for (int mtl = 0; mtl < 4; ++mtl) {
        f32x4 d = {0.f, 0.f, 0.f, 0.f};
        #pragma unroll
        for (int kf = 0; kf < 4; ++kf)
          MFMA(aq[kf], *(const bf16x8*)&k_s[swz(16 * (4 * half + mtl) + c, 8 * g + 32 * kf)], d);
        s4[mtl] = d;
      }
    }
    // ---- softmax (no max pass; |logit*invq| <= SCALING) ----
    {
      float psum[4] = {0.f, 0.f, 0.f, 0.f};
      #pragma unroll
      for (int mtl = 0; mtl < 4; ++mtl) {
        const float vmf = ((vm4 >> mtl) & 1) ? 1.f : 0.f;
        #pragma unroll
        for (int r = 0; r < 4; ++r) {
          const float e = vmf * __expf(s4[mtl][r] * invq[r]);
          s4[mtl][r] = e;
          psum[r] += e;
        }
      }
      #pragma unroll
      for (int r = 0; r < 4; ++r) {
        const float red = red16sum(psum[r]);
        if (c == 0) pB[half][band][4 * g + r] = red;
      }
    }
    LBAR();   // F: denominators published; all k_s reads done
    {
      const f32x4 sa = *(const f32x4*)&pB[0][band][4 * g];
      const f32x4 sb4 = *(const f32x4*)&pB[1][band][4 * g];
      float inv[4];
      f32x4 rn[4];
      #pragma unroll
      for (int r = 0; r < 4; ++r) {
        inv[r] = qmr[r] / (sa[r] + sb4[r]);
        rn[r] = *(const f32x4*)&r_s[16 * band + 4 * g + r][0];
      }
      #pragma unroll
      for (int mtl = 0; mtl < 4; ++mtl) {
        const int mt = 4 * half + mtl;
        const f32x4 rm = *(const f32x4*)&r_s[16 * mt + c][0];
        #pragma unroll
        for (int r = 0; r < 4; ++r) {
          const float w = s4[mtl][r] * inv[r] *
              (rn[r][0] * rm[0] + rn[r][1] * rm[1] + rn[r][2] * rm[2]);
          k_s[swz(16 * band + 4 * g + r, 16 * mt + c)] = f2bf(w);   // aw -> k_s
        }
      }
    }
    LBAR();   // G: aw visible

    // ---- PV: o = aw @ v^ ; o -> q_s (q dead) ----
    {
      bf16x8 pa[4];
      #pragma unroll
      for (int kf = 0; kf < 4; ++kf)
        pa[kf] = *(const bf16x8*)&k_s[swz(16 * band + c, 8 * g + 32 * kf)];
      #pragma unroll
      for (int htl = 0; htl < 4; ++htl) {
        f32x4 d = {0.f, 0.f, 0.f, 0.f};
        #pragma unroll
        for (int kf = 0; kf < 4; ++kf)
          MFMA(pa[kf], *(const bf16x8*)&vT_s[swz(16 * (4 * half + htl) + c, 8 * g + 32 * kf)], d);
        #pragma unroll
        for (int r = 0; r < 4; ++r)
          q_s[swz(16 * band + 4 * g + r, 16 * (4 * half + htl) + c)] = f2bf(d[r]);
      }
    }
    WVM(0);   // ow0/ow1 staged long ago -> free drain (cross-wave via next barrier)
    LBAR();   // H: o visible; ow chunks complete block-wide

    // ---- phase 4: x = LN(residual + o @ out_w + out_b) ----
    f32x4 dv[2];
    dv[0] = (f32x4){0,0,0,0}; dv[1] = (f32x4){0,0,0,0};
    {
      bf16x8 ao[4];
      #pragma unroll
      for (int kf = 0; kf < 4; ++kf)
        ao[kf] = *(const bf16x8*)&q_s[swz(16 * band + c, 8 * g + 32 * kf)];
      #pragma unroll
      for (int kh = 0; kh < 2; ++kh) {
        const u16* sb = stg + ((base + 6 + kh) % 3) * 4096;
        #pragma unroll
        for (int ntl = 0; ntl < 2; ++ntl) {
          const int col = 16 * (2 * half + ntl) + c;
          #pragma unroll
          for (int kfl = 0; kfl < 2; ++kfl)
            MFMA(ao[2 * kh + kfl], rdfrag(sb, col, 4 * kfl + g), dv[ntl]);
        }
      }
    }
    if (l + 1 < LAYERS)   // prefetch next layer's first chunk (buf free since ss5)
      stage8k(wt_hi, (long)(l + 1) * (F3 * ED) + (long)2 * 4096, 64,
              stg + ((base + 8) % 3) * 4096, wave, lane);
    {
      #pragma unroll
      for (int ntl = 0; ntl < 2; ++ntl) {
        const int e0 = 16 * (2 * half + ntl) + c;
        #pragma unroll
        for (int r = 0; r < 4; ++r)
          dv[ntl][r] += obv[ntl] + x_s[16 * band + 4 * g + r][e0];
      }
      #pragma unroll
      for (int r = 0; r < 4; ++r) {
        const float sx = red16sum(dv[0][r] + dv[1][r]);
        const float sxx = red16sum(dv[0][r] * dv[0][r] + dv[1][r] * dv[1][r]);
        if (c == 0) { pA[half][band][4 * g + r] = sx; pB[half][band][4 * g + r] = sxx; }
      }
    }
    LBAR();   // I
    {
      const f32x4 xa = *(const f32x4*)&pA[0][band][4 * g];
      const f32x4 xb = *(const f32x4*)&pA[1][band][4 * g];
      const f32x4 ya = *(const f32x4*)&pB[0][band][4 * g];
      const f32x4 yb = *(const f32x4*)&pB[1][band][4 * g];
      #pragma unroll
      for (int r = 0; r < 4; ++r) {
        const int nrow = 16 * band + 4 * g + r;
        const float mu = (xa[r] + xb[r]) * (1.f / 64.f);
        const float ex2 = (ya[r] + yb[r]) * (1.f / 64.f);
        const float rs = rsqrtf(fmaxf(ex2 - mu * mu, 0.f) + LN_EPS);
        if (nrow < NNEI) {
          #pragma unroll
          for (int ntl = 0; ntl < 2; ++ntl) {
            const int e0 = 16 * (2 * half + ntl) + c;
            const float y = (dv[ntl][r] - mu) * rs * ggv[ntl] + bbv[ntl];
            if (l + 1 < LAYERS) {
              x_s[nrow][e0] = y;
            } else {
              const long oidx = (long)b * (NNEI * ED) + (long)nrow * ED + e0;
              if (f32f) ((float*)out)[oidx] = y;
              else      ((u16*)out)[oidx] = f2bf(y);
            }
          }
        }
      }
    }
    if (l + 1 < LAYERS) LBAR();   // P: x ready for next layer (c2' stays in flight)
  }
}

extern "C" void kernel_launch(void* const* d_in, const int* in_sizes, int n_in,
                              void* d_out, int out_size, void* d_ws, size_t ws_size,
                              hipStream_t stream) {
  (void)in_sizes; (void)n_in; (void)out_size; (void)ws_size;
  const void* G = d_in[0];
  const void* mask = d_in[1];
  const void* rr = d_in[2];
  const void* in_w = d_in[3];
  const void* in_b = d_in[4];
  const void* out_w = d_in[5];
  const void* out_b = d_in[6];
  const void* ln_g = d_in[7];
  const void* ln_b = d_in[8];

  int* flags = (int*)d_ws;
  u16* wt_hi = (u16*)((char*)d_ws + 256);
  u16* ow_hi = wt_hi + LAYERS * F3 * ED;

  detect_kernel<<<dim3(1), dim3(256), 0, stream>>>((const u16*)G, (const u8*)mask, flags);
  prep_kernel<<<dim3(96), dim3(512), 0, stream>>>(in_w, out_w, wt_hi, ow_hi, flags);
  nwa_kernel<<<dim3(NB), dim3(T), 0, stream>>>(
      G, mask, rr, in_b, out_b, ln_g, ln_b, wt_hi, ow_hi, d_out, flags);
}